// Round 2
// baseline (322.598 us; speedup 1.0000x reference)
//
#include <hip/hip_runtime.h>
#include <stdint.h>

#define BB 8
#define LL 2048
#define DT 32
#define HID 544
#define REGP 5.0f
#define BETA0 0.4f
#define BETA1 0.3f
#define EPSV 1e-6f

// Kernel A: per-row (b,i): hidden_vector (544 f32) + 4 fused dot-product
// scalars into ws (biases folded; gate side pre-scaled by -REG).
__global__ __launch_bounds__(256) void prep_k(
    const int* __restrict__ etype, const float* __restrict__ etime,
    const float* __restrict__ wtpos, const float* __restrict__ temb,
    const float* __restrict__ wl, const float* __restrict__ wg,
    const float* __restrict__ blp, const float* __restrict__ bgp,
    float* __restrict__ hidden,
    float* __restrict__ pa, float* __restrict__ pbl,
    float* __restrict__ ga5, float* __restrict__ gb5)
{
    const int row = blockIdx.x;          // b*L + i
    const int i = row & (LL - 1);
    const int tid = threadIdx.x;
    const float t = etime[row];

    // div_term[k] = exp(-k * ln(10000)/256), k in [0,256)
    const float c = -0.03597789207803197f;   // -ln(10000)/256
    float divt = expf((float)tid * c);
    float arc = fmaf((float)i, divt, t * wtpos[tid]);
    size_t hbase = (size_t)row * HID;
    hidden[hbase + tid]       = sinf(arc);
    hidden[hbase + 256 + tid] = cosf(arc);

    if (tid < 32) {
        int ty = etype[row];
        float te = temb[ty * DT + tid];
        hidden[hbase + 512 + tid] = te;
        float va = te * wl[tid];
        float vb = te * wl[32 + tid];
        float vc = te * wg[tid];
        float vd = te * wg[32 + tid];
        #pragma unroll
        for (int m = 16; m > 0; m >>= 1) {
            va += __shfl_xor(va, m, 64);
            vb += __shfl_xor(vb, m, 64);
            vc += __shfl_xor(vc, m, 64);
            vd += __shfl_xor(vd, m, 64);
        }
        if (tid == 0) {
            pa[row]  = va;                       // j-side lengthscale
            pbl[row] = vb + blp[0];              // i-side lengthscale + bias
            ga5[row] = -REGP * vc;               // j-side gate, pre-scaled
            gb5[row] = -REGP * (vd + bgp[0]);    // i-side gate + bias, scaled
        }
    }
}

// Kernel B: scores + t_diff (f32). Grid (j-half, i-tile, b); 256 threads,
// each thread owns 4 consecutive j (float4 stores, fully coalesced),
// loops over 8 i rows reusing j-side registers.
__global__ __launch_bounds__(256) void pair_k(
    const float* __restrict__ etime,
    const float* __restrict__ pa, const float* __restrict__ pbl,
    const float* __restrict__ ga5, const float* __restrict__ gb5,
    float* __restrict__ scores, float* __restrict__ tdiff)
{
    const int b  = blockIdx.z;
    const int i0 = blockIdx.y << 3;
    const int j0 = (blockIdx.x << 10) + (threadIdx.x << 2);
    const int rowb = b * LL;

    const float4 tj = *(const float4*)(etime + rowb + j0);
    const float4 pj = *(const float4*)(pa + rowb + j0);
    const float4 gj = *(const float4*)(ga5 + rowb + j0);

    #pragma unroll
    for (int ii = 0; ii < 8; ++ii) {
        const int i = i0 + ii;
        const float ti  = etime[rowb + i];
        const float pbi = pbl[rowb + i];
        const float gbi = gb5[rowb + i];
        const size_t base = ((size_t)(rowb + i) << 11) + j0;

        float4 dd;
        dd.x = fabsf(tj.x - ti);
        dd.y = fabsf(tj.y - ti);
        dd.z = fabsf(tj.z - ti);
        dd.w = fabsf(tj.w - ti);
        *(float4*)(tdiff + base) = dd;

        float4 sc;
        if (j0 < i) {
            float pjv[4] = {pj.x, pj.y, pj.z, pj.w};
            float gjv[4] = {gj.x, gj.y, gj.z, gj.w};
            float dv[4]  = {dd.x, dd.y, dd.z, dd.w};
            float s[4];
            #pragma unroll
            for (int e = 0; e < 4; ++e) {
                float l  = __logf(1.0f + __expf(pjv[e] + pbi)) + EPSV;
                float rl = __builtin_amdgcn_rcpf(l);
                float u  = dv[e] * rl;
                float kse = __expf(-0.5f * u * u);
                float kex = __expf(-u);
                float g   = __builtin_amdgcn_rcpf(1.0f + __expf(gjv[e] + gbi));
                float v   = g * fmaf(BETA0, kse, BETA1 * kex);
                s[e] = ((j0 + e) < i) ? v : 0.0f;
            }
            sc.x = s[0]; sc.y = s[1]; sc.z = s[2]; sc.w = s[3];
        } else {
            sc.x = 0.0f; sc.y = 0.0f; sc.z = 0.0f; sc.w = 0.0f;
        }
        *(float4*)(scores + base) = sc;
    }
}

extern "C" void kernel_launch(void* const* d_in, const int* in_sizes, int n_in,
                              void* d_out, int out_size, void* d_ws, size_t ws_size,
                              hipStream_t stream) {
    const int*   etype = (const int*)d_in[0];
    const float* etime = (const float*)d_in[1];
    // d_in[2] arrival_times: unused by the reference
    const float* wtpos = (const float*)d_in[3];
    const float* temb  = (const float*)d_in[4];
    const float* wl    = (const float*)d_in[5];
    const float* blp   = (const float*)d_in[6];
    const float* wg    = (const float*)d_in[7];
    const float* bgp   = (const float*)d_in[8];

    float* out    = (float*)d_out;
    float* scores = out;                                  // [8,2048,2048]
    float* hidden = out + (size_t)BB * LL * LL;           // [8,2048,544]
    float* tdiff  = hidden + (size_t)BB * LL * HID;       // [8,2048,2048]

    float* pa  = (float*)d_ws;
    float* pbl = pa + BB * LL;
    float* ga5 = pbl + BB * LL;
    float* gb5 = ga5 + BB * LL;

    prep_k<<<BB * LL, 256, 0, stream>>>(etype, etime, wtpos, temb, wl, wg,
                                        blp, bgp, hidden, pa, pbl, ga5, gb5);
    pair_k<<<dim3(2, LL / 8, BB), 256, 0, stream>>>(etime, pa, pbl, ga5, gb5,
                                                    scores, tdiff);
}